// Round 11
// baseline (4744.593 us; speedup 1.0000x reference)
//
#include <hip/hip_runtime.h>

#define T_STEPS 1024
#define BATCH 32
#define HID 512
#define KDIM 512     // input size == HID

typedef __attribute__((ext_vector_type(8))) short short8;
typedef __attribute__((ext_vector_type(4))) float floatx4;
typedef __attribute__((ext_vector_type(4))) int int4v;

__device__ __forceinline__ unsigned short f2bf(float f) {
  union { float f; unsigned u; } v; v.f = f;
  return (unsigned short)((v.u + 0x7FFFu + ((v.u >> 16) & 1u)) >> 16);
}
__device__ __forceinline__ float fsigmoid(float x) {
  return 1.0f / (1.0f + __expf(-x));
}
__device__ __forceinline__ float ftanh(float x) {
  return 2.0f / (1.0f + __expf(-2.0f * x)) - 1.0f;
}

// issue 8 coalesced 16B exchange reads (sc0 sc1: bypass L1+L2, read at LLC —
// required for cross-XCD visibility). Loads are left IN FLIGHT: caller waits
// with counted s_waitcnt + sched_barrier(0) before reading v[] (rule #18).
__device__ __forceinline__ void issue_burst(const unsigned* base, int tid,
                                            int4v v[8]) {
#pragma unroll
  for (int g = 0; g < 8; ++g) {
    const unsigned* p = base + 4 * (tid + g * 512);
    asm volatile("global_load_dwordx4 %0, %1, off sc0 sc1"
                 : "=&v"(v[g]) : "v"(p) : "memory");
  }
}

// ---------------------------------------------------------------------------
// init: zero the (h|seq) dword ping-pong buffers with agent-scope stores so
// the persistent kernel's sc1 polls never see stale poison.
// Zero == (h=0 | seq=0), which is exactly what step-0 consumers poll for.
// ---------------------------------------------------------------------------
__global__ void init_kernel(unsigned* __restrict__ hbuf_u) {  // 65536 dwords
  int idx = blockIdx.x * 256 + threadIdx.x;
  __hip_atomic_store(&hbuf_u[idx], 0u, __ATOMIC_RELAXED, __HIP_MEMORY_SCOPE_AGENT);
}

__global__ void merge_kernel(float* __restrict__ out,
                             const float* __restrict__ add, int n4) {
  int i = blockIdx.x * 256 + threadIdx.x;
  int stride = gridDim.x * 256;
  for (; i < n4; i += stride) {
    float4 a = ((const float4*)add)[i];
    float4 o = ((float4*)out)[i];
    o.x += a.x; o.y += a.y; o.z += a.z; o.w += a.w;
    ((float4*)out)[i] = o;
  }
}

// ---------------------------------------------------------------------------
// Persistent bidirectional zoneout-LSTM. 64 blocks x 512 thr.
// blocks 0..31: forward, 32..63: backward. Block owns 16 hidden units.
// Wave w = (mh = w>>2 batch-half, ug = w&3 unit-group); full-K MFMA
// accumulation; gate<->batch redistribution via in-register 4x4 quad
// transpose (R10, proven).
//
// WAIT DISCIPLINE (this round's change — the load-drain audit):
//  - __syncthreads() emits s_waitcnt vmcnt(0) before s_barrier, so it DRAINS
//    any in-flight global loads. B1 is therefore a RAW barrier
//    (lgkmcnt(0) + s_barrier): the poll burst issued at the step top stays
//    in flight across it.
//  - Poll burst is DOUBLE-SAMPLED: bursts A and B issued back-to-back at the
//    step top (after the register-only f2bf pack that retires the x
//    prefetch). First check waits vmcnt(8) -> A retired, B (sampled ~RT/2
//    later) still flying. Stale-A -> vmcnt(0) + check B: retry costs ~50cy
//    instead of a full serial RT. Double-stale -> reload loop (rare).
//  - x(t+1) prefetch issues AFTER B2 (__syncthreads), so B2 drains only the
//    near-retired B burst; the prefetch is waited at the NEXT step's f2bf
//    pack by a precise compiler vmcnt (no inline asm between issue and use),
//    which does NOT wait the younger publish/out store acks.
// h-exchange protocol itself is R8/R10-proven: dword = (bf16 h | seq16<<16),
// seq = s+1, flagless, self-validating, ping-pong x2 (overwrite-safe: a
// block can only publish s+1 after every block published s, which implies
// every block consumed s-1 from the buffer being overwritten).
// ---------------------------------------------------------------------------
__global__ __launch_bounds__(512) void lstm_persist(
    const float* __restrict__ X,           // [1024, 32, 512]
    const float* __restrict__ Wih,         // [2048, 512]
    const float* __restrict__ Whh,         // [2048, 512]
    const float* __restrict__ bih,         // [2048]
    const float* __restrict__ bhh,         // [2048]
    float* __restrict__ out,               // [1024*32*512]
    unsigned* __restrict__ hw,             // [2][2][32][512] dwords (h|seq)
    float* __restrict__ obwd) {            // bwd out buffer (split) or null
  __shared__ unsigned short xs[32][520];   // staged x(t) bf16, +8 pad
  __shared__ unsigned short hs[32][520];   // staged h(s-1) bf16, +8 pad

  const int tid = threadIdx.x;
  const int bid = blockIdx.x;
  const int dir = bid >> 5;
  const int bsl = bid & 31;
  const int u0 = bsl * 16;

  unsigned* hwD = hw + dir * 2 * (BATCH * HID);   // per-direction dword region

  const int w = tid >> 6, lane = tid & 63;
  const int mh = w >> 2;          // batch half (0..1)
  const int ug = w & 3;           // unit group (4 units)
  const int colx = lane & 15, q = lane >> 4;
  const int g = colx & 3;         // quad pos: gate col at MFMA, batch-sub after transpose
  const int ul = colx >> 2;       // unit within group
  const int unit = u0 + ug * 4 + ul;        // global hidden unit of this lane
  const int b_lane = mh * 16 + q * 4 + g;   // batch row of this lane (post-transpose)

  // Preload full-K B-fragments: W row = gate(g)*HID + unit, K = 512.
  short8 bwh[16], bwx[16];
  {
    const size_t roff = (size_t)(g * HID + unit) * KDIM + q * 8;
    const float* wrh = Whh + roff;
    const float* wrx = Wih + roff;
#pragma unroll
    for (int ks = 0; ks < 16; ++ks) {
      float4 h0 = *(const float4*)(wrh + ks * 32);
      float4 h1 = *(const float4*)(wrh + ks * 32 + 4);
      union { unsigned short u[8]; short8 v; } pk;
      pk.u[0] = f2bf(h0.x); pk.u[1] = f2bf(h0.y); pk.u[2] = f2bf(h0.z); pk.u[3] = f2bf(h0.w);
      pk.u[4] = f2bf(h1.x); pk.u[5] = f2bf(h1.y); pk.u[6] = f2bf(h1.z); pk.u[7] = f2bf(h1.w);
      bwh[ks] = pk.v;
      float4 x0 = *(const float4*)(wrx + ks * 32);
      float4 x1 = *(const float4*)(wrx + ks * 32 + 4);
      union { unsigned short u[8]; short8 v; } px;
      px.u[0] = f2bf(x0.x); px.u[1] = f2bf(x0.y); px.u[2] = f2bf(x0.z); px.u[3] = f2bf(x0.w);
      px.u[4] = f2bf(x1.x); px.u[5] = f2bf(x1.y); px.u[6] = f2bf(x1.z); px.u[7] = f2bf(x1.w);
      bwx[ks] = px.v;
    }
  }

  // Per-lane biases: all 4 gates of this lane's unit.
  const float bias0 = bih[0 * HID + unit] + bhh[0 * HID + unit];
  const float bias1 = bih[1 * HID + unit] + bhh[1 * HID + unit];
  const float bias2 = bih[2 * HID + unit] + bhh[2 * HID + unit];
  const float bias3 = bih[3 * HID + unit] + bhh[3 * HID + unit];

  float c_st = 0.f, h_prev = 0.f;

  float* odst = nullptr;
  if (obwd) odst = dir ? obwd : out;   // split-store mode

  // ---- prologue: prefetch x(t0) into registers ----
  float4 xr[8];
  {
    const int t0 = dir ? (T_STEPS - 1) : 0;
    const float* xt = X + (size_t)t0 * BATCH * KDIM;
#pragma unroll
    for (int r = 0; r < 8; ++r) {
      int idx = tid + r * 512;
      xr[r] = *(const float4*)(xt + (size_t)(idx >> 7) * KDIM + (idx & 127) * 4);
    }
  }

  for (int s = 0; s < T_STEPS; ++s) {
    const int t = dir ? (T_STEPS - 1 - s) : s;

    // ---- (1) register-only f2bf pack: retires x prefetch via a precise
    //      compiler vmcnt (publish/out acks are younger -> not waited) ----
    uint2 pk[8];
#pragma unroll
    for (int r = 0; r < 8; ++r) {
      union { unsigned short u[4]; uint2 v; } p;
      p.u[0] = f2bf(xr[r].x); p.u[1] = f2bf(xr[r].y);
      p.u[2] = f2bf(xr[r].z); p.u[3] = f2bf(xr[r].w);
      pk[r] = p.v;
    }

    // ---- (2) issue double-sampled poll bursts A, B ----
    const unsigned* hq = hwD + (s & 1) * (BATCH * HID);
    int4v vA[8], vB[8];
    issue_burst(hq, tid, vA);
    issue_burst(hq, tid, vB);

    // ---- (3) xs stores ----
#pragma unroll
    for (int r = 0; r < 8; ++r) {
      int idx = tid + r * 512;
      *(uint2*)&xs[idx >> 7][(idx & 127) * 4] = pk[r];
    }

    // ---- (4) B1: RAW barrier (lgkm only) — bursts stay in flight ----
    asm volatile("s_waitcnt lgkmcnt(0)" ::: "memory");
    __builtin_amdgcn_s_barrier();

    // ---- (5) x-projection MFMAs, full K (burst in flight) ----
    floatx4 acc = {0.f, 0.f, 0.f, 0.f};
    {
      const unsigned short* ap = &xs[mh * 16 + colx][q * 8];
#pragma unroll
      for (int ks = 0; ks < 16; ++ks) {
        short8 a = *(const short8*)(ap + ks * 32);
        acc = __builtin_amdgcn_mfma_f32_16x16x32_bf16(a, bwx[ks], acc, 0, 0, 0);
      }
    }

    // ---- (6) first check on A (vmcnt(8): B still flying); fallbacks ----
    {
      const unsigned rep = (unsigned)s << 16;
      asm volatile("s_waitcnt vmcnt(8)" ::: "memory");
      __builtin_amdgcn_sched_barrier(0);
      unsigned bad = 0;
#pragma unroll
      for (int gg = 0; gg < 8; ++gg) {
        bad |= ((unsigned)vA[gg].x ^ rep);
        bad |= ((unsigned)vA[gg].y ^ rep);
        bad |= ((unsigned)vA[gg].z ^ rep);
        bad |= ((unsigned)vA[gg].w ^ rep);
      }
      if (bad & 0xFFFF0000u) {
        // A stale -> B was sampled ~RT/2 later; check it (already ~retired)
        asm volatile("s_waitcnt vmcnt(0)" ::: "memory");
        __builtin_amdgcn_sched_barrier(0);
        for (;;) {
          unsigned bad2 = 0;
#pragma unroll
          for (int gg = 0; gg < 8; ++gg) {
            bad2 |= ((unsigned)vB[gg].x ^ rep);
            bad2 |= ((unsigned)vB[gg].y ^ rep);
            bad2 |= ((unsigned)vB[gg].z ^ rep);
            bad2 |= ((unsigned)vB[gg].w ^ rep);
          }
          if (!(bad2 & 0xFFFF0000u)) break;
          issue_burst(hq, tid, vB);
          asm volatile("s_waitcnt vmcnt(0)" ::: "memory");
          __builtin_amdgcn_sched_barrier(0);
        }
#pragma unroll
        for (int gg = 0; gg < 8; ++gg) vA[gg] = vB[gg];
      }
    }

    // ---- (7) stage h(s-1) -> LDS (pack 4 low-halves per 16B read) ----
#pragma unroll
    for (int gg = 0; gg < 8; ++gg) {
      int c = tid + gg * 512;               // dwordx4 chunk index 0..4095
      int row = c >> 7;                     // batch
      int col = (c & 127) << 2;             // unit column
      uint2 hpk;
      hpk.x = ((unsigned)vA[gg].x & 0xFFFFu) | ((unsigned)vA[gg].y << 16);
      hpk.y = ((unsigned)vA[gg].z & 0xFFFFu) | ((unsigned)vA[gg].w << 16);
      *(uint2*)&hs[row][col] = hpk;
    }
    // ---- (8) B2: full __syncthreads (drains only near-retired B burst) ----
    __syncthreads();

    // ---- (9) NOW issue x(t+1) prefetch: flies under h-MFMA/pointwise/
    //      publish; waited at next step's pack with a precise vmcnt ----
    {
      const int sn = (s + 1 < T_STEPS) ? (s + 1) : s;
      const int tn = dir ? (T_STEPS - 1 - sn) : sn;
      const float* xt = X + (size_t)tn * BATCH * KDIM;
#pragma unroll
      for (int r = 0; r < 8; ++r) {
        int idx = tid + r * 512;
        xr[r] = *(const float4*)(xt + (size_t)(idx >> 7) * KDIM + (idx & 127) * 4);
      }
    }

    // ---- (10) h-projection MFMAs, full K ----
    {
      const unsigned short* ap = &hs[mh * 16 + colx][q * 8];
#pragma unroll
      for (int ks = 0; ks < 16; ++ks) {
        short8 a = *(const short8*)(ap + ks * 32);
        acc = __builtin_amdgcn_mfma_f32_16x16x32_bf16(a, bwh[ks], acc, 0, 0, 0);
      }
    }

    // ---- (11) in-register 4x4 quad transpose (gates <-> batch-subs) ----
    float f0, f1, f2, f3;
    {
      float u0s = __shfl_xor(acc[0], 2), u1s = __shfl_xor(acc[1], 2);
      float u2s = __shfl_xor(acc[2], 2), u3s = __shfl_xor(acc[3], 2);
      bool hi = (g & 2) != 0;
      float w0 = hi ? u2s : acc[0];
      float w1 = hi ? u3s : acc[1];
      float w2 = hi ? acc[2] : u0s;
      float w3 = hi ? acc[3] : u1s;
      float z0 = __shfl_xor(w0, 1), z1 = __shfl_xor(w1, 1);
      float z2 = __shfl_xor(w2, 1), z3 = __shfl_xor(w3, 1);
      bool od = (g & 1) != 0;
      f0 = od ? z1 : w0;
      f1 = od ? w1 : z0;
      f2 = od ? z3 : w2;
      f3 = od ? w3 : z2;
    }

    // ---- pointwise LSTM cell + zoneout (per-lane: batch b_lane, unit) ----
    float gi = f0 + bias0;
    float gf = f1 + bias1;
    float gg2 = f2 + bias2;
    float go = f3 + bias3;
    float si = fsigmoid(gi);
    float sf = fsigmoid(gf);
    float tg = ftanh(gg2);
    float so = fsigmoid(go);
    float c_new = sf * c_st + si * tg;
    float h_new = so * ftanh(c_new);
    c_st = 0.9f * c_new + 0.1f * c_st;
    float h = 0.9f * h_new + 0.1f * h_prev;
    h_prev = h;

    // ---- (12) publish h: per-lane (h|seq) dword, agent-scope (proven) ----
    {
      unsigned D = (unsigned)f2bf(h) | ((unsigned)(s + 1) << 16);
      unsigned* hop = hwD + ((s + 1) & 1) * (BATCH * HID);
      __hip_atomic_store(&hop[b_lane * HID + unit], D,
                         __ATOMIC_RELAXED, __HIP_MEMORY_SCOPE_AGENT);
    }

    // off the critical path: output write (plain cached store: L2 ack only)
    {
      size_t oidx = (size_t)(t * BATCH + b_lane) * HID + unit;
      if (odst) odst[oidx] = h;
      else atomicAdd(out + oidx, h);   // fallback: tiny workspace
    }
  }
}

// ---------------------------------------------------------------------------
extern "C" void kernel_launch(void* const* d_in, const int* in_sizes, int n_in,
                              void* d_out, int out_size, void* d_ws, size_t ws_size,
                              hipStream_t stream) {
  const float* X   = (const float*)d_in[0];
  const float* Wih = (const float*)d_in[1];
  const float* Whh = (const float*)d_in[2];
  const float* bih = (const float*)d_in[3];
  const float* bhh = (const float*)d_in[4];
  float* out = (float*)d_out;

  // workspace layout:
  //   [0, 256KB):      hw = [2 dir][2 buf][32][512] (h|seq) dwords (256 KB)
  //   [1MB, 65MB):     bwd-direction output buffer (split-store mode)
  unsigned* hw = (unsigned*)d_ws;                     // 65536 dwords

  const size_t OB_OFF = (size_t)1 << 20;
  const size_t OB_BYTES = (size_t)T_STEPS * BATCH * HID * sizeof(float); // 64MB

  float* obwd = nullptr;
  if (ws_size >= OB_OFF + OB_BYTES)
    obwd = (float*)((char*)d_ws + OB_OFF);

  if (!obwd)   // fallback: atomicAdd accumulation needs zeroed out
    hipMemsetAsync(d_out, 0, (size_t)out_size * sizeof(float), stream);

  hipLaunchKernelGGL(init_kernel, dim3(256), dim3(256), 0, stream, hw);
  hipLaunchKernelGGL(lstm_persist, dim3(64), dim3(512), 0, stream,
                     X, Wih, Whh, bih, bhh, out, hw, obwd);
  if (obwd)
    hipLaunchKernelGGL(merge_kernel, dim3(2048), dim3(256), 0, stream,
                       out, obwd, (T_STEPS * BATCH * HID) / 4);
}

// Round 13
// 3749.678 us; speedup vs baseline: 1.2653x; 1.2653x over previous
//
#include <hip/hip_runtime.h>

#define T_STEPS 1024
#define BATCH 32
#define HID 512
#define KDIM 512     // input size == HID

typedef __attribute__((ext_vector_type(8))) short short8;
typedef __attribute__((ext_vector_type(4))) float floatx4;
typedef __attribute__((ext_vector_type(4))) int int4v;

__device__ __forceinline__ unsigned short f2bf(float f) {
  union { float f; unsigned u; } v; v.f = f;
  return (unsigned short)((v.u + 0x7FFFu + ((v.u >> 16) & 1u)) >> 16);
}
__device__ __forceinline__ float fsigmoid(float x) {
  return 1.0f / (1.0f + __expf(-x));
}
__device__ __forceinline__ float ftanh(float x) {
  return 2.0f / (1.0f + __expf(-2.0f * x)) - 1.0f;
}

// issue 8 coalesced 16B exchange reads (sc0 sc1: bypass L1+L2, read at LLC —
// required for cross-XCD visibility). Loads are left IN FLIGHT at issue;
// EVERY issue is paired with a vmcnt(0)+sched_barrier(0) before any use of
// v[] AND before any possible register reuse (R12 lesson: an unwaited asm
// load's destination register can be reallocated by the compiler and then
// clobbered when the load lands — GPU fault).
__device__ __forceinline__ void issue_burst(const unsigned* base, int tid,
                                            int4v v[8]) {
#pragma unroll
  for (int g = 0; g < 8; ++g) {
    const unsigned* p = base + 4 * (tid + g * 512);
    asm volatile("global_load_dwordx4 %0, %1, off sc0 sc1"
                 : "=&v"(v[g]) : "v"(p) : "memory");
  }
}

// ---------------------------------------------------------------------------
// init: zero the (h|seq) dword ping-pong buffers with agent-scope stores so
// the persistent kernel's sc1 polls never see stale poison.
// Zero == (h=0 | seq=0), which is exactly what step-0 consumers poll for.
// ---------------------------------------------------------------------------
__global__ void init_kernel(unsigned* __restrict__ hbuf_u) {  // 65536 dwords
  int idx = blockIdx.x * 256 + threadIdx.x;
  __hip_atomic_store(&hbuf_u[idx], 0u, __ATOMIC_RELAXED, __HIP_MEMORY_SCOPE_AGENT);
}

__global__ void merge_kernel(float* __restrict__ out,
                             const float* __restrict__ add, int n4) {
  int i = blockIdx.x * 256 + threadIdx.x;
  int stride = gridDim.x * 256;
  for (; i < n4; i += stride) {
    float4 a = ((const float4*)add)[i];
    float4 o = ((float4*)out)[i];
    o.x += a.x; o.y += a.y; o.z += a.z; o.w += a.w;
    ((float4*)out)[i] = o;
  }
}

// ---------------------------------------------------------------------------
// Persistent bidirectional zoneout-LSTM. 64 blocks x 512 thr.
// blocks 0..31: forward, 32..63: backward. Block owns 16 hidden units.
// Wave w = (mh batch-half, ug unit-group); full-K MFMA accumulation;
// gate<->batch redistribution via in-register 4x4 quad transpose (R10).
//
// R13 = R10 structure with a SINGLE poll burst, fully retired before use:
//  - burst A issued after the x pack (samples the LLC ~RT after the
//    producers' publishes have landed — R11 showed sampling earlier is
//    systematically stale);
//  - x-MFMA (~700cy) runs under A's flight;
//  - vmcnt(0) + sched_barrier(0) retires A (plus the step-old publish/out
//    store acks) before the check — no in-flight asm loads ever cross a
//    region where their registers could be reused (R12 crash class);
//  - stale -> tight reload loop (1 RT/iter, rare in steady state);
//  - B1 raw barrier (lgkm only) keeps A flying; B2 full __syncthreads is
//    ~free (queue empty); x(t+1) prefetch issued after B2, waited at the
//    next step's pack by a precise compiler vmcnt (queue fully
//    compiler-tracked: 8 xr loads + publish + out store only).
// h-exchange protocol (proven): dword = (bf16 h | seq16<<16), seq = s+1,
// flagless, self-validating, ping-pong x2 (overwrite-safe by construction).
// ---------------------------------------------------------------------------
__global__ __launch_bounds__(512) void lstm_persist(
    const float* __restrict__ X,           // [1024, 32, 512]
    const float* __restrict__ Wih,         // [2048, 512]
    const float* __restrict__ Whh,         // [2048, 512]
    const float* __restrict__ bih,         // [2048]
    const float* __restrict__ bhh,         // [2048]
    float* __restrict__ out,               // [1024*32*512]
    unsigned* __restrict__ hw,             // [2][2][32][512] dwords (h|seq)
    float* __restrict__ obwd) {            // bwd out buffer (split) or null
  __shared__ unsigned short xs[32][520];   // staged x(t) bf16, +8 pad
  __shared__ unsigned short hs[32][520];   // staged h(s-1) bf16, +8 pad

  const int tid = threadIdx.x;
  const int bid = blockIdx.x;
  const int dir = bid >> 5;
  const int bsl = bid & 31;
  const int u0 = bsl * 16;

  unsigned* hwD = hw + dir * 2 * (BATCH * HID);   // per-direction dword region

  const int w = tid >> 6, lane = tid & 63;
  const int mh = w >> 2;          // batch half (0..1)
  const int ug = w & 3;           // unit group (4 units)
  const int colx = lane & 15, q = lane >> 4;
  const int g = colx & 3;         // quad pos: gate col at MFMA, batch-sub after
  const int ul = colx >> 2;       // unit within group
  const int unit = u0 + ug * 4 + ul;        // global hidden unit of this lane
  const int b_lane = mh * 16 + q * 4 + g;   // batch row of this lane

  // Preload full-K B-fragments: W row = gate(g)*HID + unit, K = 512.
  short8 bwh[16], bwx[16];
  {
    const size_t roff = (size_t)(g * HID + unit) * KDIM + q * 8;
    const float* wrh = Whh + roff;
    const float* wrx = Wih + roff;
#pragma unroll
    for (int ks = 0; ks < 16; ++ks) {
      float4 h0 = *(const float4*)(wrh + ks * 32);
      float4 h1 = *(const float4*)(wrh + ks * 32 + 4);
      union { unsigned short u[8]; short8 v; } pkv;
      pkv.u[0] = f2bf(h0.x); pkv.u[1] = f2bf(h0.y); pkv.u[2] = f2bf(h0.z); pkv.u[3] = f2bf(h0.w);
      pkv.u[4] = f2bf(h1.x); pkv.u[5] = f2bf(h1.y); pkv.u[6] = f2bf(h1.z); pkv.u[7] = f2bf(h1.w);
      bwh[ks] = pkv.v;
      float4 x0 = *(const float4*)(wrx + ks * 32);
      float4 x1 = *(const float4*)(wrx + ks * 32 + 4);
      union { unsigned short u[8]; short8 v; } pxv;
      pxv.u[0] = f2bf(x0.x); pxv.u[1] = f2bf(x0.y); pxv.u[2] = f2bf(x0.z); pxv.u[3] = f2bf(x0.w);
      pxv.u[4] = f2bf(x1.x); pxv.u[5] = f2bf(x1.y); pxv.u[6] = f2bf(x1.z); pxv.u[7] = f2bf(x1.w);
      bwx[ks] = pxv.v;
    }
  }

  // Per-lane biases: all 4 gates of this lane's unit.
  const float bias0 = bih[0 * HID + unit] + bhh[0 * HID + unit];
  const float bias1 = bih[1 * HID + unit] + bhh[1 * HID + unit];
  const float bias2 = bih[2 * HID + unit] + bhh[2 * HID + unit];
  const float bias3 = bih[3 * HID + unit] + bhh[3 * HID + unit];

  float c_st = 0.f, h_prev = 0.f;

  float* odst = nullptr;
  if (obwd) odst = dir ? obwd : out;   // split-store mode

  // ---- prologue: prefetch x(t0) into registers ----
  float4 xr[8];
  {
    const int t0 = dir ? (T_STEPS - 1) : 0;
    const float* xt = X + (size_t)t0 * BATCH * KDIM;
#pragma unroll
    for (int r = 0; r < 8; ++r) {
      int idx = tid + r * 512;
      xr[r] = *(const float4*)(xt + (size_t)(idx >> 7) * KDIM + (idx & 127) * 4);
    }
  }

  for (int s = 0; s < T_STEPS; ++s) {
    const int t = dir ? (T_STEPS - 1 - s) : s;

    // ---- (1) register-only f2bf pack: retires x prefetch via a precise
    //      compiler vmcnt (publish/out acks are younger -> not waited;
    //      queue is fully compiler-tracked: no asm loads in flight here) ----
    uint2 pk[8];
#pragma unroll
    for (int r = 0; r < 8; ++r) {
      union { unsigned short u[4]; uint2 v; } p;
      p.u[0] = f2bf(xr[r].x); p.u[1] = f2bf(xr[r].y);
      p.u[2] = f2bf(xr[r].z); p.u[3] = f2bf(xr[r].w);
      pk[r] = p.v;
    }
    __builtin_amdgcn_sched_barrier(0);   // keep the asm burst below the pack

    // ---- (2) issue single poll burst A ----
    const unsigned* hq = hwD + (s & 1) * (BATCH * HID);
    int4v vA[8];
    issue_burst(hq, tid, vA);

    // ---- (3) xs stores ----
#pragma unroll
    for (int r = 0; r < 8; ++r) {
      int idx = tid + r * 512;
      *(uint2*)&xs[idx >> 7][(idx & 127) * 4] = pk[r];
    }

    // ---- (4) B1: RAW barrier (lgkm only) — A stays in flight ----
    asm volatile("s_waitcnt lgkmcnt(0)" ::: "memory");
    __builtin_amdgcn_s_barrier();

    // ---- (5) x-projection MFMAs, full K (A in flight underneath) ----
    floatx4 acc = {0.f, 0.f, 0.f, 0.f};
    {
      const unsigned short* ap = &xs[mh * 16 + colx][q * 8];
#pragma unroll
      for (int ks = 0; ks < 16; ++ks) {
        short8 a = *(const short8*)(ap + ks * 32);
        acc = __builtin_amdgcn_mfma_f32_16x16x32_bf16(a, bwx[ks], acc, 0, 0, 0);
      }
    }

    // ---- (6) retire A fully, then check; stale -> reload loop ----
    {
      const unsigned rep = (unsigned)s << 16;
      asm volatile("s_waitcnt vmcnt(0)" ::: "memory");
      __builtin_amdgcn_sched_barrier(0);   // rule #18: pin reads after wait
      for (;;) {
        unsigned bad = 0;
#pragma unroll
        for (int gg = 0; gg < 8; ++gg) {
          bad |= ((unsigned)vA[gg].x ^ rep);
          bad |= ((unsigned)vA[gg].y ^ rep);
          bad |= ((unsigned)vA[gg].z ^ rep);
          bad |= ((unsigned)vA[gg].w ^ rep);
        }
        if (!(bad & 0xFFFF0000u)) break;
        issue_burst(hq, tid, vA);
        asm volatile("s_waitcnt vmcnt(0)" ::: "memory");
        __builtin_amdgcn_sched_barrier(0);
      }
    }

    // ---- (7) stage h(s-1) -> LDS (pack 4 low-halves per 16B read) ----
#pragma unroll
    for (int gg = 0; gg < 8; ++gg) {
      int c = tid + gg * 512;               // dwordx4 chunk index 0..4095
      int row = c >> 7;                     // batch
      int col = (c & 127) << 2;             // unit column
      uint2 hpk;
      hpk.x = ((unsigned)vA[gg].x & 0xFFFFu) | ((unsigned)vA[gg].y << 16);
      hpk.y = ((unsigned)vA[gg].z & 0xFFFFu) | ((unsigned)vA[gg].w << 16);
      *(uint2*)&hs[row][col] = hpk;
    }
    // ---- (8) B2: full __syncthreads (queue empty: ~free) ----
    __syncthreads();

    // ---- (9) issue x(t+1) prefetch: flies under h-MFMA/pointwise/publish;
    //      waited at next step's pack with a precise compiler vmcnt ----
    {
      const int sn = (s + 1 < T_STEPS) ? (s + 1) : s;
      const int tn = dir ? (T_STEPS - 1 - sn) : sn;
      const float* xt = X + (size_t)tn * BATCH * KDIM;
#pragma unroll
      for (int r = 0; r < 8; ++r) {
        int idx = tid + r * 512;
        xr[r] = *(const float4*)(xt + (size_t)(idx >> 7) * KDIM + (idx & 127) * 4);
      }
    }

    // ---- (10) h-projection MFMAs, full K ----
    {
      const unsigned short* ap = &hs[mh * 16 + colx][q * 8];
#pragma unroll
      for (int ks = 0; ks < 16; ++ks) {
        short8 a = *(const short8*)(ap + ks * 32);
        acc = __builtin_amdgcn_mfma_f32_16x16x32_bf16(a, bwh[ks], acc, 0, 0, 0);
      }
    }

    // ---- (11) in-register 4x4 quad transpose (gates <-> batch-subs) ----
    float f0, f1, f2, f3;
    {
      float u0s = __shfl_xor(acc[0], 2), u1s = __shfl_xor(acc[1], 2);
      float u2s = __shfl_xor(acc[2], 2), u3s = __shfl_xor(acc[3], 2);
      bool hi = (g & 2) != 0;
      float w0 = hi ? u2s : acc[0];
      float w1 = hi ? u3s : acc[1];
      float w2 = hi ? acc[2] : u0s;
      float w3 = hi ? acc[3] : u1s;
      float z0 = __shfl_xor(w0, 1), z1 = __shfl_xor(w1, 1);
      float z2 = __shfl_xor(w2, 1), z3 = __shfl_xor(w3, 1);
      bool od = (g & 1) != 0;
      f0 = od ? z1 : w0;
      f1 = od ? w1 : z0;
      f2 = od ? z3 : w2;
      f3 = od ? w3 : z2;
    }

    // ---- pointwise LSTM cell + zoneout (per-lane: batch b_lane, unit) ----
    float gi = f0 + bias0;
    float gf = f1 + bias1;
    float gg2 = f2 + bias2;
    float go = f3 + bias3;
    float si = fsigmoid(gi);
    float sf = fsigmoid(gf);
    float tg = ftanh(gg2);
    float so = fsigmoid(go);
    float c_new = sf * c_st + si * tg;
    float h_new = so * ftanh(c_new);
    c_st = 0.9f * c_new + 0.1f * c_st;
    float h = 0.9f * h_new + 0.1f * h_prev;
    h_prev = h;

    // ---- (12) publish h: per-lane (h|seq) dword, agent-scope (proven) ----
    {
      unsigned D = (unsigned)f2bf(h) | ((unsigned)(s + 1) << 16);
      unsigned* hop = hwD + ((s + 1) & 1) * (BATCH * HID);
      __hip_atomic_store(&hop[b_lane * HID + unit], D,
                         __ATOMIC_RELAXED, __HIP_MEMORY_SCOPE_AGENT);
    }

    // off the critical path: output write (plain cached store: L2 ack only)
    {
      size_t oidx = (size_t)(t * BATCH + b_lane) * HID + unit;
      if (odst) odst[oidx] = h;
      else atomicAdd(out + oidx, h);   // fallback: tiny workspace
    }
  }
}

// ---------------------------------------------------------------------------
extern "C" void kernel_launch(void* const* d_in, const int* in_sizes, int n_in,
                              void* d_out, int out_size, void* d_ws, size_t ws_size,
                              hipStream_t stream) {
  const float* X   = (const float*)d_in[0];
  const float* Wih = (const float*)d_in[1];
  const float* Whh = (const float*)d_in[2];
  const float* bih = (const float*)d_in[3];
  const float* bhh = (const float*)d_in[4];
  float* out = (float*)d_out;

  // workspace layout:
  //   [0, 256KB):      hw = [2 dir][2 buf][32][512] (h|seq) dwords (256 KB)
  //   [1MB, 65MB):     bwd-direction output buffer (split-store mode)
  unsigned* hw = (unsigned*)d_ws;                     // 65536 dwords

  const size_t OB_OFF = (size_t)1 << 20;
  const size_t OB_BYTES = (size_t)T_STEPS * BATCH * HID * sizeof(float); // 64MB

  float* obwd = nullptr;
  if (ws_size >= OB_OFF + OB_BYTES)
    obwd = (float*)((char*)d_ws + OB_OFF);

  if (!obwd)   // fallback: atomicAdd accumulation needs zeroed out
    hipMemsetAsync(d_out, 0, (size_t)out_size * sizeof(float), stream);

  hipLaunchKernelGGL(init_kernel, dim3(256), dim3(256), 0, stream, hw);
  hipLaunchKernelGGL(lstm_persist, dim3(64), dim3(512), 0, stream,
                     X, Wih, Whh, bih, bhh, out, hw, obwd);
  if (obwd)
    hipLaunchKernelGGL(merge_kernel, dim3(2048), dim3(256), 0, stream,
                       out, obwd, (T_STEPS * BATCH * HID) / 4);
}

// Round 14
// 3234.296 us; speedup vs baseline: 1.4670x; 1.1593x over previous
//
#include <hip/hip_runtime.h>

#define T_STEPS 1024
#define BATCH 32
#define HID 512
#define KDIM 512     // input size == HID

typedef __attribute__((ext_vector_type(8))) short short8;
typedef __attribute__((ext_vector_type(4))) float floatx4;
typedef __attribute__((ext_vector_type(4))) int int4v;

__device__ __forceinline__ unsigned short f2bf(float f) {
  union { float f; unsigned u; } v; v.f = f;
  return (unsigned short)((v.u + 0x7FFFu + ((v.u >> 16) & 1u)) >> 16);
}
__device__ __forceinline__ float fsigmoid(float x) {
  return 1.0f / (1.0f + __expf(-x));
}
__device__ __forceinline__ float ftanh(float x) {
  return 2.0f / (1.0f + __expf(-2.0f * x)) - 1.0f;
}

// issue 8 coalesced 16B exchange reads (sc0 sc1: bypass L1+L2, read at LLC —
// required for cross-XCD visibility). Loads are left IN FLIGHT at issue;
// EVERY issue is paired with a vmcnt(0)+sched_barrier(0) before any use of
// v[] AND before any possible register reuse (R12 lesson: an unwaited asm
// load's destination register can be reallocated by the compiler and then
// clobbered when the load lands — GPU fault).
__device__ __forceinline__ void issue_burst(const unsigned* base, int tid,
                                            int4v v[8]) {
#pragma unroll
  for (int g = 0; g < 8; ++g) {
    const unsigned* p = base + 4 * (tid + g * 512);
    asm volatile("global_load_dwordx4 %0, %1, off sc0 sc1"
                 : "=&v"(v[g]) : "v"(p) : "memory");
  }
}

// ---------------------------------------------------------------------------
// init: zero the (h|seq) dword ping-pong buffers with agent-scope stores so
// the persistent kernel's sc1 polls never see stale poison.
// Zero == (h=0 | seq=0), which is exactly what step-0 consumers poll for.
// ---------------------------------------------------------------------------
__global__ void init_kernel(unsigned* __restrict__ hbuf_u) {  // 65536 dwords
  int idx = blockIdx.x * 256 + threadIdx.x;
  __hip_atomic_store(&hbuf_u[idx], 0u, __ATOMIC_RELAXED, __HIP_MEMORY_SCOPE_AGENT);
}

__global__ void merge_kernel(float* __restrict__ out,
                             const float* __restrict__ add, int n4) {
  int i = blockIdx.x * 256 + threadIdx.x;
  int stride = gridDim.x * 256;
  for (; i < n4; i += stride) {
    float4 a = ((const float4*)add)[i];
    float4 o = ((float4*)out)[i];
    o.x += a.x; o.y += a.y; o.z += a.z; o.w += a.w;
    ((float4*)out)[i] = o;
  }
}

// ---------------------------------------------------------------------------
// Persistent bidirectional zoneout-LSTM. 64 blocks x 512 thr.
// blocks 0..31: forward, 32..63: backward. Block owns 16 hidden units.
// Wave w = (mh batch-half, ug unit-group); full-K MFMA accumulation;
// gate<->batch redistribution via in-register 4x4 quad transpose (R10).
//
// BURST TIMING LAW (R11+R13, twice-confirmed): the poll's LLC sample must
// arrive >= publish-one-way (~500-800cy) AFTER the slowest producer's
// publish issue. Issuing the burst after B1 (~700cy into the step) is the
// empirically optimal point (R10's 3176us); issuing it at the step top
// (R13) samples early -> systematically stale -> +1 full RT per step.
//
// Step structure (R14 = R10 timing + R13's audited micro-wins):
//  (1) pack xr (compiler-precise vmcnt(2): xr retired, younger publish/out
//      acks NOT waited; no asm loads in flight here)
//  (2) xs stores  (3) B1 RAW barrier (lgkm only - no vmcnt drain)
//  (4) issue burst A  (5) x-MFMA full K under A's flight
//  (6) vmcnt(0)+sched_barrier(0), check; stale -> tight reload loop
//  (7) stage hs  (8) B2 full __syncthreads (queue empty: ~free)
//  (9) prefetch x(t+1) (waited at next step's pack after ~2000cy of flight)
//  (10) h-MFMA  (11) quad transpose  (12) pointwise  (13) publish + out
// h-exchange protocol (proven): dword = (bf16 h | seq16<<16), seq = s+1,
// flagless, self-validating, ping-pong x2 (overwrite-safe by construction).
// ---------------------------------------------------------------------------
__global__ __launch_bounds__(512) void lstm_persist(
    const float* __restrict__ X,           // [1024, 32, 512]
    const float* __restrict__ Wih,         // [2048, 512]
    const float* __restrict__ Whh,         // [2048, 512]
    const float* __restrict__ bih,         // [2048]
    const float* __restrict__ bhh,         // [2048]
    float* __restrict__ out,               // [1024*32*512]
    unsigned* __restrict__ hw,             // [2][2][32][512] dwords (h|seq)
    float* __restrict__ obwd) {            // bwd out buffer (split) or null
  __shared__ unsigned short xs[32][520];   // staged x(t) bf16, +8 pad
  __shared__ unsigned short hs[32][520];   // staged h(s-1) bf16, +8 pad

  const int tid = threadIdx.x;
  const int bid = blockIdx.x;
  const int dir = bid >> 5;
  const int bsl = bid & 31;
  const int u0 = bsl * 16;

  unsigned* hwD = hw + dir * 2 * (BATCH * HID);   // per-direction dword region

  const int w = tid >> 6, lane = tid & 63;
  const int mh = w >> 2;          // batch half (0..1)
  const int ug = w & 3;           // unit group (4 units)
  const int colx = lane & 15, q = lane >> 4;
  const int g = colx & 3;         // quad pos: gate col at MFMA, batch-sub after
  const int ul = colx >> 2;       // unit within group
  const int unit = u0 + ug * 4 + ul;        // global hidden unit of this lane
  const int b_lane = mh * 16 + q * 4 + g;   // batch row of this lane

  // Preload full-K B-fragments: W row = gate(g)*HID + unit, K = 512.
  short8 bwh[16], bwx[16];
  {
    const size_t roff = (size_t)(g * HID + unit) * KDIM + q * 8;
    const float* wrh = Whh + roff;
    const float* wrx = Wih + roff;
#pragma unroll
    for (int ks = 0; ks < 16; ++ks) {
      float4 h0 = *(const float4*)(wrh + ks * 32);
      float4 h1 = *(const float4*)(wrh + ks * 32 + 4);
      union { unsigned short u[8]; short8 v; } pkv;
      pkv.u[0] = f2bf(h0.x); pkv.u[1] = f2bf(h0.y); pkv.u[2] = f2bf(h0.z); pkv.u[3] = f2bf(h0.w);
      pkv.u[4] = f2bf(h1.x); pkv.u[5] = f2bf(h1.y); pkv.u[6] = f2bf(h1.z); pkv.u[7] = f2bf(h1.w);
      bwh[ks] = pkv.v;
      float4 x0 = *(const float4*)(wrx + ks * 32);
      float4 x1 = *(const float4*)(wrx + ks * 32 + 4);
      union { unsigned short u[8]; short8 v; } pxv;
      pxv.u[0] = f2bf(x0.x); pxv.u[1] = f2bf(x0.y); pxv.u[2] = f2bf(x0.z); pxv.u[3] = f2bf(x0.w);
      pxv.u[4] = f2bf(x1.x); pxv.u[5] = f2bf(x1.y); pxv.u[6] = f2bf(x1.z); pxv.u[7] = f2bf(x1.w);
      bwx[ks] = pxv.v;
    }
  }

  // Per-lane biases: all 4 gates of this lane's unit.
  const float bias0 = bih[0 * HID + unit] + bhh[0 * HID + unit];
  const float bias1 = bih[1 * HID + unit] + bhh[1 * HID + unit];
  const float bias2 = bih[2 * HID + unit] + bhh[2 * HID + unit];
  const float bias3 = bih[3 * HID + unit] + bhh[3 * HID + unit];

  float c_st = 0.f, h_prev = 0.f;

  float* odst = nullptr;
  if (obwd) odst = dir ? obwd : out;   // split-store mode

  // ---- prologue: prefetch x(t0) into registers ----
  float4 xr[8];
  {
    const int t0 = dir ? (T_STEPS - 1) : 0;
    const float* xt = X + (size_t)t0 * BATCH * KDIM;
#pragma unroll
    for (int r = 0; r < 8; ++r) {
      int idx = tid + r * 512;
      xr[r] = *(const float4*)(xt + (size_t)(idx >> 7) * KDIM + (idx & 127) * 4);
    }
  }

  for (int s = 0; s < T_STEPS; ++s) {
    const int t = dir ? (T_STEPS - 1 - s) : s;

    // ---- (1) register-only f2bf pack: retires x prefetch via a precise
    //      compiler vmcnt (publish/out acks are younger -> not waited) ----
    uint2 pk[8];
#pragma unroll
    for (int r = 0; r < 8; ++r) {
      union { unsigned short u[4]; uint2 v; } p;
      p.u[0] = f2bf(xr[r].x); p.u[1] = f2bf(xr[r].y);
      p.u[2] = f2bf(xr[r].z); p.u[3] = f2bf(xr[r].w);
      pk[r] = p.v;
    }

    // ---- (2) xs stores ----
#pragma unroll
    for (int r = 0; r < 8; ++r) {
      int idx = tid + r * 512;
      *(uint2*)&xs[idx >> 7][(idx & 127) * 4] = pk[r];
    }

    // ---- (3) B1: RAW barrier (lgkm only) — no vmcnt drain ----
    asm volatile("s_waitcnt lgkmcnt(0)" ::: "memory");
    __builtin_amdgcn_s_barrier();

    // ---- (4) issue poll burst A (~700cy into the step: past the
    //      publish-one-way window -> fresh in steady state) ----
    const unsigned* hq = hwD + (s & 1) * (BATCH * HID);
    int4v vA[8];
    issue_burst(hq, tid, vA);

    // ---- (5) x-projection MFMAs, full K (A in flight underneath) ----
    floatx4 acc = {0.f, 0.f, 0.f, 0.f};
    {
      const unsigned short* ap = &xs[mh * 16 + colx][q * 8];
#pragma unroll
      for (int ks = 0; ks < 16; ++ks) {
        short8 a = *(const short8*)(ap + ks * 32);
        acc = __builtin_amdgcn_mfma_f32_16x16x32_bf16(a, bwx[ks], acc, 0, 0, 0);
      }
    }

    // ---- (6) retire A fully, then check; stale -> reload loop ----
    {
      const unsigned rep = (unsigned)s << 16;
      asm volatile("s_waitcnt vmcnt(0)" ::: "memory");
      __builtin_amdgcn_sched_barrier(0);   // rule #18: pin reads after wait
      for (;;) {
        unsigned bad = 0;
#pragma unroll
        for (int gg = 0; gg < 8; ++gg) {
          bad |= ((unsigned)vA[gg].x ^ rep);
          bad |= ((unsigned)vA[gg].y ^ rep);
          bad |= ((unsigned)vA[gg].z ^ rep);
          bad |= ((unsigned)vA[gg].w ^ rep);
        }
        if (!(bad & 0xFFFF0000u)) break;
        issue_burst(hq, tid, vA);
        asm volatile("s_waitcnt vmcnt(0)" ::: "memory");
        __builtin_amdgcn_sched_barrier(0);
      }
    }

    // ---- (7) stage h(s-1) -> LDS (pack 4 low-halves per 16B read) ----
#pragma unroll
    for (int gg = 0; gg < 8; ++gg) {
      int c = tid + gg * 512;               // dwordx4 chunk index 0..4095
      int row = c >> 7;                     // batch
      int col = (c & 127) << 2;             // unit column
      uint2 hpk;
      hpk.x = ((unsigned)vA[gg].x & 0xFFFFu) | ((unsigned)vA[gg].y << 16);
      hpk.y = ((unsigned)vA[gg].z & 0xFFFFu) | ((unsigned)vA[gg].w << 16);
      *(uint2*)&hs[row][col] = hpk;
    }
    // ---- (8) B2: full __syncthreads (queue empty: ~free) ----
    __syncthreads();

    // ---- (9) issue x(t+1) prefetch: flies under h-MFMA/pointwise/publish;
    //      waited at next step's pack with a precise compiler vmcnt ----
    {
      const int sn = (s + 1 < T_STEPS) ? (s + 1) : s;
      const int tn = dir ? (T_STEPS - 1 - sn) : sn;
      const float* xt = X + (size_t)tn * BATCH * KDIM;
#pragma unroll
      for (int r = 0; r < 8; ++r) {
        int idx = tid + r * 512;
        xr[r] = *(const float4*)(xt + (size_t)(idx >> 7) * KDIM + (idx & 127) * 4);
      }
    }

    // ---- (10) h-projection MFMAs, full K ----
    {
      const unsigned short* ap = &hs[mh * 16 + colx][q * 8];
#pragma unroll
      for (int ks = 0; ks < 16; ++ks) {
        short8 a = *(const short8*)(ap + ks * 32);
        acc = __builtin_amdgcn_mfma_f32_16x16x32_bf16(a, bwh[ks], acc, 0, 0, 0);
      }
    }

    // ---- (11) in-register 4x4 quad transpose (gates <-> batch-subs) ----
    float f0, f1, f2, f3;
    {
      float u0s = __shfl_xor(acc[0], 2), u1s = __shfl_xor(acc[1], 2);
      float u2s = __shfl_xor(acc[2], 2), u3s = __shfl_xor(acc[3], 2);
      bool hi = (g & 2) != 0;
      float w0 = hi ? u2s : acc[0];
      float w1 = hi ? u3s : acc[1];
      float w2 = hi ? acc[2] : u0s;
      float w3 = hi ? acc[3] : u1s;
      float z0 = __shfl_xor(w0, 1), z1 = __shfl_xor(w1, 1);
      float z2 = __shfl_xor(w2, 1), z3 = __shfl_xor(w3, 1);
      bool od = (g & 1) != 0;
      f0 = od ? z1 : w0;
      f1 = od ? w1 : z0;
      f2 = od ? z3 : w2;
      f3 = od ? w3 : z2;
    }

    // ---- pointwise LSTM cell + zoneout (per-lane: batch b_lane, unit) ----
    float gi = f0 + bias0;
    float gf = f1 + bias1;
    float gg2 = f2 + bias2;
    float go = f3 + bias3;
    float si = fsigmoid(gi);
    float sf = fsigmoid(gf);
    float tg = ftanh(gg2);
    float so = fsigmoid(go);
    float c_new = sf * c_st + si * tg;
    float h_new = so * ftanh(c_new);
    c_st = 0.9f * c_new + 0.1f * c_st;
    float h = 0.9f * h_new + 0.1f * h_prev;
    h_prev = h;

    // ---- (13) publish h: per-lane (h|seq) dword, agent-scope (proven) ----
    {
      unsigned D = (unsigned)f2bf(h) | ((unsigned)(s + 1) << 16);
      unsigned* hop = hwD + ((s + 1) & 1) * (BATCH * HID);
      __hip_atomic_store(&hop[b_lane * HID + unit], D,
                         __ATOMIC_RELAXED, __HIP_MEMORY_SCOPE_AGENT);
    }

    // off the critical path: output write (plain cached store: L2 ack only)
    {
      size_t oidx = (size_t)(t * BATCH + b_lane) * HID + unit;
      if (odst) odst[oidx] = h;
      else atomicAdd(out + oidx, h);   // fallback: tiny workspace
    }
  }
}

// ---------------------------------------------------------------------------
extern "C" void kernel_launch(void* const* d_in, const int* in_sizes, int n_in,
                              void* d_out, int out_size, void* d_ws, size_t ws_size,
                              hipStream_t stream) {
  const float* X   = (const float*)d_in[0];
  const float* Wih = (const float*)d_in[1];
  const float* Whh = (const float*)d_in[2];
  const float* bih = (const float*)d_in[3];
  const float* bhh = (const float*)d_in[4];
  float* out = (float*)d_out;

  // workspace layout:
  //   [0, 256KB):      hw = [2 dir][2 buf][32][512] (h|seq) dwords (256 KB)
  //   [1MB, 65MB):     bwd-direction output buffer (split-store mode)
  unsigned* hw = (unsigned*)d_ws;                     // 65536 dwords

  const size_t OB_OFF = (size_t)1 << 20;
  const size_t OB_BYTES = (size_t)T_STEPS * BATCH * HID * sizeof(float); // 64MB

  float* obwd = nullptr;
  if (ws_size >= OB_OFF + OB_BYTES)
    obwd = (float*)((char*)d_ws + OB_OFF);

  if (!obwd)   // fallback: atomicAdd accumulation needs zeroed out
    hipMemsetAsync(d_out, 0, (size_t)out_size * sizeof(float), stream);

  hipLaunchKernelGGL(init_kernel, dim3(256), dim3(256), 0, stream, hw);
  hipLaunchKernelGGL(lstm_persist, dim3(64), dim3(512), 0, stream,
                     X, Wih, Whh, bih, bhh, out, hw, obwd);
  if (obwd)
    hipLaunchKernelGGL(merge_kernel, dim3(2048), dim3(256), 0, stream,
                       out, obwd, (T_STEPS * BATCH * HID) / 4);
}